// Round 6
// baseline (937.505 us; speedup 1.0000x reference)
//
#include <hip/hip_runtime.h>
#include <hip/hip_bf16.h>
#include <stdint.h>

#define N_NODES 50000
#define F_IN 256
#define HID 128
#define NH 8
#define DH 16
#define NE 800000
#define NM 3
#define NOUT 8
#define NEG 0.2f
#define NROWS (N_NODES * NM)   // 150000 semantic rows
#define LDP 68                 // padded uint (k-pair) LDS stride (k_semw tile)
#define LD3 36                 // padded stride for k_fcproj [64][32] tiles
#define NBLK 196               // ceil(50000/256) scan blocks
#define BSH 8                  // bucket shift: 256 dst per bucket
#define NBUCK 196              // ceil(50000/256)
#define EPB 8192               // edges per binning block

__device__ __forceinline__ float bf2f(unsigned short u) {
    union { unsigned int ui; float f; } cv;
    cv.ui = ((unsigned int)u) << 16;
    return cv.f;
}
__device__ __forceinline__ unsigned short f2bf(float x) {
    __hip_bfloat16 b = __float2bfloat16(x);
    return reinterpret_cast<const unsigned short&>(b);
}
__device__ __forceinline__ float bflo(unsigned int u) {
    union { unsigned int x; float f; } c; c.x = u << 16; return c.f;
}
__device__ __forceinline__ float bfhi(unsigned int u) {
    union { unsigned int x; float f; } c; c.x = u & 0xffff0000u; return c.f;
}

// ---------------- CSR build ----------------
__global__ __launch_bounds__(256) void k_hist(const int* __restrict__ dst,
                                              int* __restrict__ deg) {
    int e = blockIdx.x * 256 + threadIdx.x;
    int m = blockIdx.y;
    if (e >= NE) return;
    atomicAdd(&deg[m * N_NODES + dst[(size_t)m * NE + e]], 1);
}

__global__ __launch_bounds__(256) void k_scan1(const int* __restrict__ deg,
                                               int* __restrict__ pfx,
                                               int* __restrict__ blksum) {
    __shared__ int sc[256];
    int m = blockIdx.y, blk = blockIdx.x, t = threadIdx.x;
    int i = blk * 256 + t;
    int v = (i < N_NODES) ? deg[m * N_NODES + i] : 0;
    sc[t] = v;
    __syncthreads();
    #pragma unroll
    for (int o = 1; o < 256; o <<= 1) {
        int add = (t >= o) ? sc[t - o] : 0;
        __syncthreads();
        sc[t] += add;
        __syncthreads();
    }
    if (i < N_NODES) pfx[m * N_NODES + i] = sc[t] - v;
    if (t == 255) blksum[m * NBLK + blk] = sc[255];
}

__global__ __launch_bounds__(256) void k_scan2(const int* __restrict__ blksum,
                                               int* __restrict__ blkbase) {
    __shared__ int sc[256];
    int m = blockIdx.x, t = threadIdx.x;
    int v = (t < NBLK) ? blksum[m * NBLK + t] : 0;
    sc[t] = v;
    __syncthreads();
    #pragma unroll
    for (int o = 1; o < 256; o <<= 1) {
        int add = (t >= o) ? sc[t - o] : 0;
        __syncthreads();
        sc[t] += add;
        __syncthreads();
    }
    if (t < NBLK) blkbase[m * NBLK + t] = sc[t] - v;
}

__global__ __launch_bounds__(256) void k_scan3(const int* __restrict__ pfx,
                                               const int* __restrict__ blkbase,
                                               int* __restrict__ offs,
                                               int* __restrict__ dstCur,
                                               int* __restrict__ binCur) {
    int m = blockIdx.y, blk = blockIdx.x, t = threadIdx.x;
    int i = blk * 256 + t;
    if (i < N_NODES) {
        int o = blkbase[m * NBLK + blk] + pfx[m * N_NODES + i];
        offs[m * (N_NODES + 1) + i] = o;
        dstCur[m * N_NODES + i] = o;
        if ((i & 255) == 0) binCur[m * NBUCK + (i >> BSH)] = o;
    }
    if (i == 0) offs[m * (N_NODES + 1) + N_NODES] = NE;
}

// grid (ceil(NE/EPB), NM): all metapaths binned concurrently (separate pairs bufs)
__global__ __launch_bounds__(256) void k_binA2(const int* __restrict__ src0,
                                               const int* __restrict__ dst0,
                                               int* __restrict__ binCur0,
                                               int2* __restrict__ pairs0) {
    __shared__ int cnt[NBUCK];
    __shared__ int base[NBUCK];
    int m = blockIdx.y;
    const int* src = src0 + (size_t)m * NE;
    const int* dst = dst0 + (size_t)m * NE;
    int* binCur = binCur0 + (size_t)m * NBUCK;
    int2* pairs = pairs0 + (size_t)m * NE;
    int t = threadIdx.x;
    int e0 = blockIdx.x * EPB;
    int e1 = e0 + EPB; if (e1 > NE) e1 = NE;
    for (int i = t; i < NBUCK; i += 256) cnt[i] = 0;
    __syncthreads();
    for (int i = e0 + t; i < e1; i += 256)
        atomicAdd(&cnt[dst[i] >> BSH], 1);
    __syncthreads();
    for (int i = t; i < NBUCK; i += 256) {
        int c = cnt[i];
        base[i] = c ? atomicAdd(&binCur[i], c) : 0;
        cnt[i] = 0;
    }
    __syncthreads();
    for (int i = e0 + t; i < e1; i += 256) {
        int d = dst[i], s = src[i];
        int b = d >> BSH;
        int off = atomicAdd(&cnt[b], 1);
        pairs[base[b] + off] = make_int2(s, d);
    }
}

__global__ __launch_bounds__(256) void k_binB(const int2* __restrict__ pairs0,
                                              int* __restrict__ dstCur0,
                                              int* __restrict__ ssrc0) {
    int m = blockIdx.y;
    const int2* pairs = pairs0 + (size_t)m * NE;
    int* dstCur = dstCur0 + (size_t)m * N_NODES;
    int* ssrc = ssrc0 + (size_t)m * NE;
    int i = blockIdx.x * 256 + threadIdx.x;
    if (i >= NE) return;
    int2 p = pairs[i];
    int pos = atomicAdd(&dstCur[p.y], 1);
    ssrc[pos] = p.x;
}

// ---- K_attw: util[m][k][h] = sum_d Wsrc[m][k][h*16+d]*al[m][h*16+d]; same wtil/Wdst/ar ----
__global__ __launch_bounds__(128) void k_attw(const float* __restrict__ Wsrc,
                                              const float* __restrict__ Wdst,
                                              const float* __restrict__ al,
                                              const float* __restrict__ ar,
                                              float* __restrict__ util,
                                              float* __restrict__ wtil) {
    int m = blockIdx.x;
    int k = threadIdx.x;
    const float* ws = Wsrc + ((size_t)m * HID + k) * HID;
    const float* wd = Wdst + ((size_t)m * HID + k) * HID;
    const float* alm = al + m * HID;
    const float* arm = ar + m * HID;
    #pragma unroll
    for (int hh = 0; hh < NH; hh++) {
        float su = 0.f, sw = 0.f;
        #pragma unroll
        for (int d = 0; d < DH; d++) {
            su += ws[hh * DH + d] * alm[hh * DH + d];
            sw += wd[hh * DH + d] * arm[hh * DH + d];
        }
        util[((size_t)m * HID + k) * NH + hh] = su;
        wtil[((size_t)m * HID + k) * NH + hh] = sw;
    }
}

// ---- K1+K2 fused: h = feat@Wfc + b (registers), h-tile -> LDS as packed bf16,
// then for each metapath m: fs16 = bf16(h@Wsrc[m]); el = h@util[m]; er = h@wtil[m].
// 32 rows/block (grid 1563): round-3/5 used 64 rows -> only 782 blocks = 3/CU,
// occupancy pinned at 26% (grid-starved, not LDS/VGPR). 2 rows per thread.
// NOTE: no min-waves clamp (round-4's (256,8) forced VGPR=32 -> 932 MB spill).
__global__ __launch_bounds__(256) void k_fcproj(const float* __restrict__ A,
                                                const float* __restrict__ Bfc,
                                                const float* __restrict__ bias,
                                                const float* __restrict__ Bs0,
                                                const float* __restrict__ util0,
                                                const float* __restrict__ wtil0,
                                                unsigned short* __restrict__ fs0,
                                                float* __restrict__ el0,
                                                float* __restrict__ er0) {
    __shared__ float As[64 * LD3];                        // 9.2 KB
    unsigned int* As2 = reinterpret_cast<unsigned int*>(As); // aliased bf16 h-tile
    int tid = threadIdx.x;
    int tc = tid & 15, tr = tid >> 4;   // tr 0..15, rows tr*2, tr*2+1
    int r0 = blockIdx.x * 32;
    int j0 = tc * 8;
    int rowA = tid & 31;
    int kc = tid >> 5;                  // 0..7, 8 k per group
    float acc[2][8];
    #pragma unroll
    for (int i = 0; i < 2; i++)
        #pragma unroll
        for (int c = 0; c < 8; c++) acc[i][c] = 0.f;

    int gr = r0 + rowA; if (gr > N_NODES - 1) gr = N_NODES - 1;
    // ---- phase 1: h-tile = feat @ Wfc, K in 4 chunks of 64 ----
    for (int ph = 0; ph < 4; ph++) {
        __syncthreads();
        const float* ap = A + (size_t)gr * F_IN + ph * 64 + kc * 8;
        {
            float4 v0 = ((const float4*)ap)[0];
            float4 v1 = ((const float4*)ap)[1];
            int k = kc * 8;
            As[(k + 0) * LD3 + rowA] = v0.x;
            As[(k + 1) * LD3 + rowA] = v0.y;
            As[(k + 2) * LD3 + rowA] = v0.z;
            As[(k + 3) * LD3 + rowA] = v0.w;
            As[(k + 4) * LD3 + rowA] = v1.x;
            As[(k + 5) * LD3 + rowA] = v1.y;
            As[(k + 6) * LD3 + rowA] = v1.z;
            As[(k + 7) * LD3 + rowA] = v1.w;
        }
        __syncthreads();
        const float* bp = Bfc + (size_t)(ph * 64) * HID + j0;
        #pragma unroll 4
        for (int k = 0; k < 64; k++) {
            float2 a2 = *(const float2*)&As[k * LD3 + tr * 2];
            float4 b0 = *(const float4*)&bp[(size_t)k * HID];
            float4 b1 = *(const float4*)&bp[(size_t)k * HID + 4];
            float bv[8] = {b0.x, b0.y, b0.z, b0.w, b1.x, b1.y, b1.z, b1.w};
            #pragma unroll
            for (int c = 0; c < 8; c++) {
                acc[0][c] += a2.x * bv[c];
                acc[1][c] += a2.y * bv[c];
            }
        }
    }
    // ---- phase 2: h-tile (+bias, bf16) -> LDS in the [kp][row] pair layout ----
    {
        float bb[8];
        #pragma unroll
        for (int c = 0; c < 8; c++) bb[c] = bias[j0 + c];
        __syncthreads();   // all phase-1 LDS reads done before overwrite
        #pragma unroll
        for (int i = 0; i < 2; i++) {
            int row = tr * 2 + i;
            #pragma unroll
            for (int cc = 0; cc < 4; cc++) {
                float ha = acc[i][2 * cc] + bb[2 * cc];
                float hb = acc[i][2 * cc + 1] + bb[2 * cc + 1];
                As2[(tc * 4 + cc) * LD3 + row] =
                    (unsigned int)f2bf(ha) | ((unsigned int)f2bf(hb) << 16);
            }
        }
        __syncthreads();
    }
    // ---- phase 3: per-metapath projections from the resident h-tile ----
    for (int m = 0; m < NM; m++) {
        unsigned short* fs16 = fs0 + (size_t)m * N_NODES * HID;
        float* el = el0 + (size_t)m * N_NODES * NH;
        float* er = er0 + (size_t)m * N_NODES * NH;
        const float* bp = Bs0 + (size_t)m * HID * HID + j0;
        const float* ep = ((tc < 8) ? util0 + (size_t)m * HID * NH
                                    : wtil0 + (size_t)m * HID * NH) + (tc & 7);
        float pacc[2][8];
        float ae[2];
        #pragma unroll
        for (int i = 0; i < 2; i++) {
            ae[i] = 0.f;
            #pragma unroll
            for (int c = 0; c < 8; c++) pacc[i][c] = 0.f;
        }
        #pragma unroll 2
        for (int kp = 0; kp < 64; kp++) {
            uint2 aa = *(const uint2*)&As2[kp * LD3 + tr * 2];
            int k0 = kp * 2;
            float aev[2] = {bflo(aa.x), bflo(aa.y)};
            float aov[2] = {bfhi(aa.x), bfhi(aa.y)};
            float4 b00 = *(const float4*)&bp[(size_t)k0 * HID];
            float4 b01 = *(const float4*)&bp[(size_t)k0 * HID + 4];
            float4 b10 = *(const float4*)&bp[(size_t)(k0 + 1) * HID];
            float4 b11 = *(const float4*)&bp[(size_t)(k0 + 1) * HID + 4];
            float bv0[8] = {b00.x, b00.y, b00.z, b00.w, b01.x, b01.y, b01.z, b01.w};
            float bv1[8] = {b10.x, b10.y, b10.z, b10.w, b11.x, b11.y, b11.z, b11.w};
            float e0 = ep[(size_t)k0 * NH];
            float e1 = ep[(size_t)(k0 + 1) * NH];
            #pragma unroll
            for (int i = 0; i < 2; i++) {
                #pragma unroll
                for (int c = 0; c < 8; c++)
                    pacc[i][c] += aev[i] * bv0[c] + aov[i] * bv1[c];
                ae[i] += aev[i] * e0 + aov[i] * e1;
            }
        }
        #pragma unroll
        for (int i = 0; i < 2; i++) {
            int row = r0 + tr * 2 + i;
            if (row < N_NODES) {
                union { unsigned short us[8]; uint4 v; } pk;
                #pragma unroll
                for (int c = 0; c < 8; c++) pk.us[c] = f2bf(pacc[i][c]);
                *(uint4*)&fs16[(size_t)row * HID + j0] = pk.v;
                if (tc < 8) el[row * NH + tc] = ae[i];
                else        er[row * NH + (tc - 8)] = ae[i];
            }
        }
    }
}

// ---- K3: per-dst GAT aggregation. One WAVE per dst (2 dst per 128-thr block).
// Each lane owns 2 features (uint = 2 bf16). Edge weights computed once per
// (edge, head): the 8 lanes of each head-group each handle one edge of an 8-edge
// chunk, then (src, w) are shfl-broadcast during the FMA loop. (Round-1 body:
// the explicit 2-stage pipeline variant measured slower; reverted.)
__global__ __launch_bounds__(128) void k_gat(const int* __restrict__ ssrc0,
                                             const int* __restrict__ offs0,
                                             const float* __restrict__ el0,
                                             const float* __restrict__ er0,
                                             const unsigned short* __restrict__ fs0,
                                             float* __restrict__ z) {
    int m = blockIdx.y;
    const int* ssrc = ssrc0 + (size_t)m * NE;
    const int* offs = offs0 + (size_t)m * (N_NODES + 1);
    const float* el = el0 + (size_t)m * N_NODES * NH;
    const float* er = er0 + (size_t)m * N_NODES * NH;
    const unsigned int* fsu = (const unsigned int*)(fs0 + (size_t)m * N_NODES * HID);
    int d = blockIdx.x * 2 + (threadIdx.x >> 6);
    int lane = threadIdx.x & 63;
    int hh = lane >> 3;          // head for features 2*lane, 2*lane+1
    int sub = lane & 7;          // edge slot within an 8-edge chunk
    int gbase = lane & 56;       // head-group base lane
    int s0 = offs[d], s1 = offs[d + 1];
    float erd = er[(unsigned)d * NH + hh];
    float num0 = 0.f, num1 = 0.f, denp = 0.f;
    int base = s0;
    // full 8-edge chunks
    for (; base + 8 <= s1; base += 8) {
        int s = ssrc[base + sub];
        float x = el[(unsigned)s * NH + hh] + erd;
        x = (x >= 0.f) ? x : NEG * x;
        float w = __expf(x);
        denp += w;
        #pragma unroll
        for (int t = 0; t < 8; t++) {
            int st = __shfl(s, gbase + t, 64);
            float wt = __shfl(w, gbase + t, 64);
            unsigned int u = fsu[(unsigned)st * (HID / 2) + lane];
            num0 += wt * bflo(u);
            num1 += wt * bfhi(u);
        }
    }
    // tail (n in 1..7); lanes beyond n contribute w=0
    int n = s1 - base;
    if (n > 0) {
        int s = ssrc[base + ((sub < n) ? sub : n - 1)];
        float x = el[(unsigned)s * NH + hh] + erd;
        x = (x >= 0.f) ? x : NEG * x;
        float w = (sub < n) ? __expf(x) : 0.f;
        denp += w;
        #pragma unroll 2
        for (int t = 0; t < n; t++) {
            int st = __shfl(s, gbase + t, 64);
            float wt = __shfl(w, gbase + t, 64);
            unsigned int u = fsu[(unsigned)st * (HID / 2) + lane];
            num0 += wt * bflo(u);
            num1 += wt * bfhi(u);
        }
    }
    // reduce den partials across the 8 lanes of the head-group
    denp += __shfl_xor(denp, 1, 64);
    denp += __shfl_xor(denp, 2, 64);
    denp += __shfl_xor(denp, 4, 64);
    float inv = 1.f / fmaxf(denp, 1e-9f);
    float v0 = num0 * inv, v1 = num1 * inv;
    v0 = (v0 > 0.f) ? v0 : (__expf(v0) - 1.f);
    v1 = (v1 > 0.f) ? v1 : (__expf(v1) - 1.f);
    *(float2*)&z[((size_t)d * NM + m) * HID + 2 * lane] = make_float2(v0, v1);
}

// -------- K4: w[r] = tanh(zel@W1 + b1) @ w2  (bf16 LDS A-tile; fp32 B from L2) ----
__global__ __launch_bounds__(256) void k_semw(const float* __restrict__ A,
                                              const float* __restrict__ B,
                                              const float* __restrict__ b1,
                                              const float* __restrict__ ws2,
                                              float* __restrict__ w) {
    __shared__ unsigned int As2[64 * LDP];
    int tid = threadIdx.x;
    int tc = tid & 15, tr = tid >> 4;
    int r0 = blockIdx.x * 64;
    int j0 = tc * 8;
    int rowA = tid & 63;
    int kc = tid >> 6;
    float acc[4][8];
    #pragma unroll
    for (int i = 0; i < 4; i++)
        #pragma unroll
        for (int c = 0; c < 8; c++) acc[i][c] = 0.f;

    int gr = r0 + rowA; if (gr > NROWS - 1) gr = NROWS - 1;
    const float* ap = A + (size_t)gr * HID + kc * 32;
    #pragma unroll
    for (int i = 0; i < 8; i++) {
        float4 v = ((const float4*)ap)[i];
        int kp = (kc * 32 + i * 4) >> 1;
        unsigned int p0 = (unsigned int)f2bf(v.x) | ((unsigned int)f2bf(v.y) << 16);
        unsigned int p1 = (unsigned int)f2bf(v.z) | ((unsigned int)f2bf(v.w) << 16);
        As2[kp * LDP + rowA] = p0;
        As2[(kp + 1) * LDP + rowA] = p1;
    }
    __syncthreads();
    const float* bp = B + j0;
    #pragma unroll 2
    for (int kp = 0; kp < 64; kp++) {
        uint4 aa = *(const uint4*)&As2[kp * LDP + tr * 4];
        int k0 = kp * 2;
        float aev[4] = {bflo(aa.x), bflo(aa.y), bflo(aa.z), bflo(aa.w)};
        float aov[4] = {bfhi(aa.x), bfhi(aa.y), bfhi(aa.z), bfhi(aa.w)};
        float4 b00 = *(const float4*)&bp[(size_t)k0 * HID];
        float4 b01 = *(const float4*)&bp[(size_t)k0 * HID + 4];
        float4 b10 = *(const float4*)&bp[(size_t)(k0 + 1) * HID];
        float4 b11 = *(const float4*)&bp[(size_t)(k0 + 1) * HID + 4];
        float bv0[8] = {b00.x, b00.y, b00.z, b00.w, b01.x, b01.y, b01.z, b01.w};
        float bv1[8] = {b10.x, b10.y, b10.z, b10.w, b11.x, b11.y, b11.z, b11.w};
        #pragma unroll
        for (int i = 0; i < 4; i++)
            #pragma unroll
            for (int c = 0; c < 8; c++)
                acc[i][c] += aev[i] * bv0[c] + aov[i] * bv1[c];
    }
    float bb[8], s2[8];
    #pragma unroll
    for (int c = 0; c < 8; c++) { bb[c] = b1[j0 + c]; s2[c] = ws2[j0 + c]; }
    #pragma unroll
    for (int i = 0; i < 4; i++) {
        float v = 0.f;
        #pragma unroll
        for (int c = 0; c < 8; c++) v += tanhf(acc[i][c] + bb[c]) * s2[c];
        #pragma unroll
        for (int o = 8; o > 0; o >>= 1) v += __shfl_down(v, o, 16);
        int row = r0 + tr * 4 + i;
        if (tc == 0 && row < NROWS) w[row] = v;
    }
}

// ---------------- K5: beta softmax + fused + out ----------------
__global__ __launch_bounds__(256) void k_comb(const float* __restrict__ zel,
                                              const float* __restrict__ w,
                                              const float* __restrict__ Wout,
                                              const float* __restrict__ bout,
                                              float* __restrict__ out) {
    __shared__ float fusedL[2][HID];
    int half = threadIdx.x >> 7;
    int j = threadIdx.x & 127;
    int n = blockIdx.x * 2 + half;
    float w0 = w[n * NM + 0];
    float w1 = w[n * NM + 1];
    float w2 = w[n * NM + 2];
    float mx = fmaxf(w0, fmaxf(w1, w2));
    float e0 = __expf(w0 - mx);
    float e1 = __expf(w1 - mx);
    float e2 = __expf(w2 - mx);
    float inv = 1.f / (e0 + e1 + e2);
    size_t base = (size_t)n * NM * HID;
    float f = (e0 * zel[base + j] + e1 * zel[base + HID + j] + e2 * zel[base + 2 * HID + j]) * inv;
    fusedL[half][j] = f;
    __syncthreads();
    int c = j >> 4, t16 = j & 15;
    float p = 0.f;
    #pragma unroll
    for (int i = 0; i < 8; i++) {
        int jj = t16 + i * 16;
        p += fusedL[half][jj] * Wout[jj * NOUT + c];
    }
    #pragma unroll
    for (int o = 8; o > 0; o >>= 1) p += __shfl_down(p, o, 16);
    if (t16 == 0) out[n * NOUT + c] = p + bout[c];
}

extern "C" void kernel_launch(void* const* d_in, const int* in_sizes, int n_in,
                              void* d_out, int out_size, void* d_ws, size_t ws_size,
                              hipStream_t stream) {
    (void)in_sizes; (void)n_in; (void)out_size; (void)ws_size;
    const float* feat  = (const float*)d_in[0];
    const float* Wfc   = (const float*)d_in[1];
    const float* bfc   = (const float*)d_in[2];
    const float* Wsrc  = (const float*)d_in[3];
    const float* Wdst  = (const float*)d_in[4];
    const float* al    = (const float*)d_in[5];
    const float* ar    = (const float*)d_in[6];
    const float* Wsem1 = (const float*)d_in[7];
    const float* bsem1 = (const float*)d_in[8];
    const float* wsem2 = (const float*)d_in[9];
    const float* Wout  = (const float*)d_in[10];
    const float* bout  = (const float*)d_in[11];
    const int* srcI    = (const int*)d_in[12];
    const int* dstI    = (const int*)d_in[13];
    float* out = (float*)d_out;

    // fp32 section.
    float* z    = (float*)d_ws;                       // NROWS*HID
    float* el   = z  + (size_t)NROWS * HID;           // NM*N_NODES*NH
    float* er   = el + (size_t)NM * N_NODES * NH;
    float* wsc  = er + (size_t)NM * N_NODES * NH;     // NROWS
    float* util = wsc + (size_t)NROWS;                // NM*HID*NH
    float* wtil = util + (size_t)NM * HID * NH;
    unsigned short* fs16 = (unsigned short*)(wtil + (size_t)NM * HID * NH); // NM*N_NODES*HID
    // int section
    int* deg    = (int*)(fs16 + (size_t)NM * N_NODES * HID);
    int* offs   = deg    + (size_t)NM * N_NODES;
    int* ssrc   = offs   + (size_t)NM * (N_NODES + 1);
    int* pfx    = ssrc   + (size_t)NM * NE;
    int* dstCur = pfx    + (size_t)NM * N_NODES;
    int* blksum = dstCur + (size_t)NM * N_NODES;
    int* blkbase= blksum + (size_t)NM * NBLK;
    int* binCur = blkbase+ (size_t)NM * NBLK;
    // pairs (NM*NE int2 = 19.2 MB) aliases the fs16 region (38.4 MB): the CSR
    // build fully consumes pairs before k_fcproj writes fs16 (same stream).
    int2* pairs = (int2*)fs16;

    // ---- CSR build ----
    hipMemsetAsync(deg, 0, (size_t)NM * N_NODES * sizeof(int), stream);
    {
        dim3 ge((NE + 255) / 256, NM);
        dim3 gs(NBLK, NM);
        k_hist<<<ge, 256, 0, stream>>>(dstI, deg);
        k_scan1<<<gs, 256, 0, stream>>>(deg, pfx, blksum);
        k_scan2<<<NM, 256, 0, stream>>>(blksum, blkbase);
        k_scan3<<<gs, 256, 0, stream>>>(pfx, blkbase, offs, dstCur, binCur);
        dim3 gb((NE + EPB - 1) / EPB, NM);
        k_binA2<<<gb, 256, 0, stream>>>(srcI, dstI, binCur, pairs);
        dim3 gc((NE + 255) / 256, NM);
        k_binB<<<gc, 256, 0, stream>>>(pairs, dstCur, ssrc);
    }

    k_attw<<<NM, 128, 0, stream>>>(Wsrc, Wdst, al, ar, util, wtil);
    k_fcproj<<<(N_NODES + 31) / 32, 256, 0, stream>>>(feat, Wfc, bfc, Wsrc,
                                                      util, wtil, fs16, el, er);
    {
        dim3 gg(N_NODES / 2, NM);
        k_gat<<<gg, 128, 0, stream>>>(ssrc, offs, el, er, fs16, z);
    }

    k_semw<<<(NROWS + 63) / 64, 256, 0, stream>>>(z, Wsem1, bsem1, wsem2, wsc);
    k_comb<<<N_NODES / 2, 256, 0, stream>>>(z, wsc, Wout, bout, out);
}

// Round 7
// 714.784 us; speedup vs baseline: 1.3116x; 1.3116x over previous
//
#include <hip/hip_runtime.h>
#include <hip/hip_bf16.h>
#include <stdint.h>

#define N_NODES 50000
#define F_IN 256
#define HID 128
#define NH 8
#define DH 16
#define NE 800000
#define NM 3
#define NOUT 8
#define NEG 0.2f
#define NROWS (N_NODES * NM)   // 150000 semantic rows
#define LDP 68                 // padded uint (k-pair) LDS stride (k_semw tile)
#define LDH 136                // padded bf16 stride for k_fcproj h-tile
#define NBLK 196               // ceil(50000/256) scan blocks
#define BSH 8                  // bucket shift: 256 dst per bucket
#define NBUCK 196              // ceil(50000/256)
#define EPB 8192               // edges per binning block

// pack sizes (u16 elements per plane)
#define WFCP_N 65536           // 8ct * 8ks * 64 * 8
#define WSP_N  98304           // 3m * 8ct * 4ks * 64 * 8
#define UTP_N  6144            // 3m * 4ks * 64 * 8

typedef __attribute__((ext_vector_type(8))) short bfrag;
typedef __attribute__((ext_vector_type(4))) float f32x4;
union FU { uint4 u; bfrag b; };

#define MFMA(a, b, c) __builtin_amdgcn_mfma_f32_16x16x32_bf16(a, b, c, 0, 0, 0)

__device__ __forceinline__ float bf2f(unsigned short u) {
    union { unsigned int ui; float f; } cv;
    cv.ui = ((unsigned int)u) << 16;
    return cv.f;
}
__device__ __forceinline__ unsigned short f2bf(float x) {
    __hip_bfloat16 b = __float2bfloat16(x);
    return reinterpret_cast<const unsigned short&>(b);
}
__device__ __forceinline__ float bflo(unsigned int u) {
    union { unsigned int x; float f; } c; c.x = u << 16; return c.f;
}
__device__ __forceinline__ float bfhi(unsigned int u) {
    union { unsigned int x; float f; } c; c.x = u & 0xffff0000u; return c.f;
}

// ---------------- CSR build ----------------
__global__ __launch_bounds__(256) void k_hist(const int* __restrict__ dst,
                                              int* __restrict__ deg) {
    int e = blockIdx.x * 256 + threadIdx.x;
    int m = blockIdx.y;
    if (e >= NE) return;
    atomicAdd(&deg[m * N_NODES + dst[(size_t)m * NE + e]], 1);
}

__global__ __launch_bounds__(256) void k_scan1(const int* __restrict__ deg,
                                               int* __restrict__ pfx,
                                               int* __restrict__ blksum) {
    __shared__ int sc[256];
    int m = blockIdx.y, blk = blockIdx.x, t = threadIdx.x;
    int i = blk * 256 + t;
    int v = (i < N_NODES) ? deg[m * N_NODES + i] : 0;
    sc[t] = v;
    __syncthreads();
    #pragma unroll
    for (int o = 1; o < 256; o <<= 1) {
        int add = (t >= o) ? sc[t - o] : 0;
        __syncthreads();
        sc[t] += add;
        __syncthreads();
    }
    if (i < N_NODES) pfx[m * N_NODES + i] = sc[t] - v;
    if (t == 255) blksum[m * NBLK + blk] = sc[255];
}

__global__ __launch_bounds__(256) void k_scan2(const int* __restrict__ blksum,
                                               int* __restrict__ blkbase) {
    __shared__ int sc[256];
    int m = blockIdx.x, t = threadIdx.x;
    int v = (t < NBLK) ? blksum[m * NBLK + t] : 0;
    sc[t] = v;
    __syncthreads();
    #pragma unroll
    for (int o = 1; o < 256; o <<= 1) {
        int add = (t >= o) ? sc[t - o] : 0;
        __syncthreads();
        sc[t] += add;
        __syncthreads();
    }
    if (t < NBLK) blkbase[m * NBLK + t] = sc[t] - v;
}

__global__ __launch_bounds__(256) void k_scan3(const int* __restrict__ pfx,
                                               const int* __restrict__ blkbase,
                                               int* __restrict__ offs,
                                               int* __restrict__ dstCur,
                                               int* __restrict__ binCur) {
    int m = blockIdx.y, blk = blockIdx.x, t = threadIdx.x;
    int i = blk * 256 + t;
    if (i < N_NODES) {
        int o = blkbase[m * NBLK + blk] + pfx[m * N_NODES + i];
        offs[m * (N_NODES + 1) + i] = o;
        dstCur[m * N_NODES + i] = o;
        if ((i & 255) == 0) binCur[m * NBUCK + (i >> BSH)] = o;
    }
    if (i == 0) offs[m * (N_NODES + 1) + N_NODES] = NE;
}

// grid (ceil(NE/EPB), NM): all metapaths binned concurrently (separate pairs bufs)
__global__ __launch_bounds__(256) void k_binA2(const int* __restrict__ src0,
                                               const int* __restrict__ dst0,
                                               int* __restrict__ binCur0,
                                               int2* __restrict__ pairs0) {
    __shared__ int cnt[NBUCK];
    __shared__ int base[NBUCK];
    int m = blockIdx.y;
    const int* src = src0 + (size_t)m * NE;
    const int* dst = dst0 + (size_t)m * NE;
    int* binCur = binCur0 + (size_t)m * NBUCK;
    int2* pairs = pairs0 + (size_t)m * NE;
    int t = threadIdx.x;
    int e0 = blockIdx.x * EPB;
    int e1 = e0 + EPB; if (e1 > NE) e1 = NE;
    for (int i = t; i < NBUCK; i += 256) cnt[i] = 0;
    __syncthreads();
    for (int i = e0 + t; i < e1; i += 256)
        atomicAdd(&cnt[dst[i] >> BSH], 1);
    __syncthreads();
    for (int i = t; i < NBUCK; i += 256) {
        int c = cnt[i];
        base[i] = c ? atomicAdd(&binCur[i], c) : 0;
        cnt[i] = 0;
    }
    __syncthreads();
    for (int i = e0 + t; i < e1; i += 256) {
        int d = dst[i], s = src[i];
        int b = d >> BSH;
        int off = atomicAdd(&cnt[b], 1);
        pairs[base[b] + off] = make_int2(s, d);
    }
}

__global__ __launch_bounds__(256) void k_binB(const int2* __restrict__ pairs0,
                                              int* __restrict__ dstCur0,
                                              int* __restrict__ ssrc0) {
    int m = blockIdx.y;
    const int2* pairs = pairs0 + (size_t)m * NE;
    int* dstCur = dstCur0 + (size_t)m * N_NODES;
    int* ssrc = ssrc0 + (size_t)m * NE;
    int i = blockIdx.x * 256 + threadIdx.x;
    if (i >= NE) return;
    int2 p = pairs[i];
    int pos = atomicAdd(&dstCur[p.y], 1);
    ssrc[pos] = p.x;
}

// ---- K_attw: util[m][k][h] = sum_d Wsrc[m][k][h*16+d]*al[m][h*16+d]; same wtil/Wdst/ar ----
__global__ __launch_bounds__(128) void k_attw(const float* __restrict__ Wsrc,
                                              const float* __restrict__ Wdst,
                                              const float* __restrict__ al,
                                              const float* __restrict__ ar,
                                              float* __restrict__ util,
                                              float* __restrict__ wtil) {
    int m = blockIdx.x;
    int k = threadIdx.x;
    const float* ws = Wsrc + ((size_t)m * HID + k) * HID;
    const float* wd = Wdst + ((size_t)m * HID + k) * HID;
    const float* alm = al + m * HID;
    const float* arm = ar + m * HID;
    #pragma unroll
    for (int hh = 0; hh < NH; hh++) {
        float su = 0.f, sw = 0.f;
        #pragma unroll
        for (int d = 0; d < DH; d++) {
            su += ws[hh * DH + d] * alm[hh * DH + d];
            sw += wd[hh * DH + d] * arm[hh * DH + d];
        }
        util[((size_t)m * HID + k) * NH + hh] = su;
        wtil[((size_t)m * HID + k) * NH + hh] = sw;
    }
}

// ---- K_pack: pre-pack B matrices into MFMA fragment order as bf16 hi/lo planes.
// Fragment slot for K x N matrix (KS k-steps, CT col-tiles):
//   slot = (ct*KS + ks)*64 + lane; element j (0..7): k = ks*32 + (lane>>4)*8 + j,
//   n = ct*16 + (lane&15). hi = bf16(v), lo = bf16(v - fp32(hi)).
__global__ __launch_bounds__(256) void k_pack(const float* __restrict__ Wfc,
                                              const float* __restrict__ Wsrc,
                                              const float* __restrict__ util,
                                              const float* __restrict__ wtil,
                                              unsigned short* __restrict__ wfcph,
                                              unsigned short* __restrict__ wfcpl,
                                              unsigned short* __restrict__ wsph,
                                              unsigned short* __restrict__ wspl,
                                              unsigned short* __restrict__ utph,
                                              unsigned short* __restrict__ utpl) {
    int g = blockIdx.x * 256 + threadIdx.x;
    if (blockIdx.x < 16) {                   // Wfc: 4096 slots (CT=8, KS=8)
        int s = g;
        int lane = s & 63, t = s >> 6;
        int ks = t & 7, ct = t >> 3;
        int n = ct * 16 + (lane & 15);
        int kb = ks * 32 + ((lane >> 4) << 3);
        #pragma unroll
        for (int j = 0; j < 8; j++) {
            float v = Wfc[(size_t)(kb + j) * HID + n];
            unsigned short h = f2bf(v);
            wfcph[(size_t)s * 8 + j] = h;
            wfcpl[(size_t)s * 8 + j] = f2bf(v - bf2f(h));
        }
    } else if (blockIdx.x < 40) {            // Wsrc: 6144 slots (3m, CT=8, KS=4)
        int s = g - 16 * 256;
        int lane = s & 63, t = s >> 6;
        int ks = t & 3, ct = (t >> 2) & 7, m = t >> 5;
        int n = ct * 16 + (lane & 15);
        int kb = ks * 32 + ((lane >> 4) << 3);
        #pragma unroll
        for (int j = 0; j < 8; j++) {
            float v = Wsrc[((size_t)m * HID + kb + j) * HID + n];
            unsigned short h = f2bf(v);
            wsph[(size_t)s * 8 + j] = h;
            wspl[(size_t)s * 8 + j] = f2bf(v - bf2f(h));
        }
    } else {                                 // util|wtil: 768 slots (3m, CT=1, KS=4)
        int s = g - 40 * 256;
        if (s >= UTP_N / 8) return;
        int lane = s & 63, t = s >> 6;
        int ks = t & 3, m = t >> 2;
        int n = lane & 15;
        int kb = ks * 32 + ((lane >> 4) << 3);
        #pragma unroll
        for (int j = 0; j < 8; j++) {
            int k = kb + j;
            float v = (n < 8) ? util[((size_t)m * HID + k) * NH + n]
                              : wtil[((size_t)m * HID + k) * NH + (n - 8)];
            unsigned short h = f2bf(v);
            utph[(size_t)s * 8 + j] = h;
            utpl[(size_t)s * 8 + j] = f2bf(v - bf2f(h));
        }
    }
}

// ---- K1+K2 fused, MFMA version. 64 rows/block, 4 waves, wave w owns rows
// r0+16w..+15 end-to-end (NO barriers; waves independent).
// Phase 1: h = feat @ Wfc via bf16x2 split (AhBh + AhBl + AlBh; AlBl ~2^-18
// dropped) -> fp32-faithful h. Phase 2: bf16(h + bias) -> LDS (the exact values
// downstream already consumed). Phase 3 per metapath: fs16 = bf16(h @ Wsrc)
// and el/er = h @ (util|wtil) via A-exact x (Bhi + Blo) 2-pass MFMA.
// MFMA layouts (m89/m91): A lane&15=row, k=(lane>>4)*8+j; C col=lane&15,
// row=(lane>>4)*4+reg.
__global__ __launch_bounds__(256) void k_fcproj(const float* __restrict__ A,
                                                const float* __restrict__ bias,
                                                const unsigned short* __restrict__ wfcph,
                                                const unsigned short* __restrict__ wfcpl,
                                                const unsigned short* __restrict__ wsph,
                                                const unsigned short* __restrict__ wspl,
                                                const unsigned short* __restrict__ utph,
                                                const unsigned short* __restrict__ utpl,
                                                unsigned short* __restrict__ fs0,
                                                float* __restrict__ el0,
                                                float* __restrict__ er0) {
    __shared__ unsigned short hb[64 * LDH];   // 17.4 KB bf16 h-tile
    int tid = threadIdx.x;
    int w = tid >> 6, l = tid & 63;
    int lr = l & 15;       // A-row / C-col lane index
    int lq = l >> 4;       // k-block / C-row-quad index
    int r0 = blockIdx.x * 64;
    int rowA = r0 + 16 * w + lr;
    int gr = (rowA < N_NODES) ? rowA : (N_NODES - 1);

    // ---- phase 1: h-tile = feat @ Wfc (split-precision MFMA) ----
    f32x4 acc[8];
    #pragma unroll
    for (int ct = 0; ct < 8; ct++) acc[ct] = (f32x4){0.f, 0.f, 0.f, 0.f};
    const uint4* bh4 = (const uint4*)wfcph;
    const uint4* bl4 = (const uint4*)wfcpl;
    for (int ks = 0; ks < 8; ks++) {
        const float* ap = A + (size_t)gr * F_IN + ks * 32 + lq * 8;
        float4 v0 = ((const float4*)ap)[0];
        float4 v1 = ((const float4*)ap)[1];
        float av[8] = {v0.x, v0.y, v0.z, v0.w, v1.x, v1.y, v1.z, v1.w};
        bfrag ah, al;
        #pragma unroll
        for (int j = 0; j < 8; j++) {
            unsigned short h = f2bf(av[j]);
            ah[j] = (short)h;
            al[j] = (short)f2bf(av[j] - bf2f(h));
        }
        #pragma unroll
        for (int ct = 0; ct < 8; ct++) {
            FU bh, bl;
            bh.u = bh4[(ct * 8 + ks) * 64 + l];
            bl.u = bl4[(ct * 8 + ks) * 64 + l];
            acc[ct] = MFMA(ah, bh.b, acc[ct]);
            acc[ct] = MFMA(ah, bl.b, acc[ct]);
            acc[ct] = MFMA(al, bh.b, acc[ct]);
        }
    }
    // ---- phase 2: bf16(h + bias) -> LDS (wave-private rows; no barrier) ----
    #pragma unroll
    for (int ct = 0; ct < 8; ct++) {
        int col = ct * 16 + lr;
        float bb = bias[col];
        #pragma unroll
        for (int rg = 0; rg < 4; rg++) {
            int rloc = 16 * w + lq * 4 + rg;
            hb[rloc * LDH + col] = f2bf(acc[ct][rg] + bb);
        }
    }
    // ---- phase 3: per-metapath fs16 / el / er ----
    const uint4* sh4 = (const uint4*)wsph;
    const uint4* sl4 = (const uint4*)wspl;
    const uint4* uh4 = (const uint4*)utph;
    const uint4* ul4 = (const uint4*)utpl;
    for (int m = 0; m < NM; m++) {
        f32x4 acc2[8];
        f32x4 eacc = (f32x4){0.f, 0.f, 0.f, 0.f};
        #pragma unroll
        for (int ct = 0; ct < 8; ct++) acc2[ct] = (f32x4){0.f, 0.f, 0.f, 0.f};
        #pragma unroll
        for (int ks = 0; ks < 4; ks++) {
            FU a;
            a.u = *(const uint4*)&hb[(16 * w + lr) * LDH + ks * 32 + lq * 8];
            #pragma unroll
            for (int ct = 0; ct < 8; ct++) {
                FU bh, bl;
                bh.u = sh4[(m * 32 + ct * 4 + ks) * 64 + l];
                bl.u = sl4[(m * 32 + ct * 4 + ks) * 64 + l];
                acc2[ct] = MFMA(a.b, bh.b, acc2[ct]);
                acc2[ct] = MFMA(a.b, bl.b, acc2[ct]);
            }
            FU uh, ul;
            uh.u = uh4[(m * 4 + ks) * 64 + l];
            ul.u = ul4[(m * 4 + ks) * 64 + l];
            eacc = MFMA(a.b, uh.b, eacc);
            eacc = MFMA(a.b, ul.b, eacc);
        }
        unsigned short* fsm = fs0 + (size_t)m * N_NODES * HID;
        #pragma unroll
        for (int ct = 0; ct < 8; ct++) {
            #pragma unroll
            for (int rg = 0; rg < 4; rg++) {
                int row = r0 + 16 * w + lq * 4 + rg;
                if (row < N_NODES)
                    fsm[(size_t)row * HID + ct * 16 + lr] = f2bf(acc2[ct][rg]);
            }
        }
        float* elm = el0 + (size_t)m * N_NODES * NH;
        float* erm = er0 + (size_t)m * N_NODES * NH;
        #pragma unroll
        for (int rg = 0; rg < 4; rg++) {
            int row = r0 + 16 * w + lq * 4 + rg;
            if (row < N_NODES) {
                if (lr < 8) elm[(size_t)row * NH + lr] = eacc[rg];
                else        erm[(size_t)row * NH + (lr - 8)] = eacc[rg];
            }
        }
    }
}

// ---- K3: per-dst GAT aggregation. One WAVE per dst (2 dst per 128-thr block).
// (Round-1 body — best measured.)
__global__ __launch_bounds__(128) void k_gat(const int* __restrict__ ssrc0,
                                             const int* __restrict__ offs0,
                                             const float* __restrict__ el0,
                                             const float* __restrict__ er0,
                                             const unsigned short* __restrict__ fs0,
                                             float* __restrict__ z) {
    int m = blockIdx.y;
    const int* ssrc = ssrc0 + (size_t)m * NE;
    const int* offs = offs0 + (size_t)m * (N_NODES + 1);
    const float* el = el0 + (size_t)m * N_NODES * NH;
    const float* er = er0 + (size_t)m * N_NODES * NH;
    const unsigned int* fsu = (const unsigned int*)(fs0 + (size_t)m * N_NODES * HID);
    int d = blockIdx.x * 2 + (threadIdx.x >> 6);
    int lane = threadIdx.x & 63;
    int hh = lane >> 3;          // head for features 2*lane, 2*lane+1
    int sub = lane & 7;          // edge slot within an 8-edge chunk
    int gbase = lane & 56;       // head-group base lane
    int s0 = offs[d], s1 = offs[d + 1];
    float erd = er[(unsigned)d * NH + hh];
    float num0 = 0.f, num1 = 0.f, denp = 0.f;
    int base = s0;
    for (; base + 8 <= s1; base += 8) {
        int s = ssrc[base + sub];
        float x = el[(unsigned)s * NH + hh] + erd;
        x = (x >= 0.f) ? x : NEG * x;
        float w = __expf(x);
        denp += w;
        #pragma unroll
        for (int t = 0; t < 8; t++) {
            int st = __shfl(s, gbase + t, 64);
            float wt = __shfl(w, gbase + t, 64);
            unsigned int u = fsu[(unsigned)st * (HID / 2) + lane];
            num0 += wt * bflo(u);
            num1 += wt * bfhi(u);
        }
    }
    int n = s1 - base;
    if (n > 0) {
        int s = ssrc[base + ((sub < n) ? sub : n - 1)];
        float x = el[(unsigned)s * NH + hh] + erd;
        x = (x >= 0.f) ? x : NEG * x;
        float w = (sub < n) ? __expf(x) : 0.f;
        denp += w;
        #pragma unroll 2
        for (int t = 0; t < n; t++) {
            int st = __shfl(s, gbase + t, 64);
            float wt = __shfl(w, gbase + t, 64);
            unsigned int u = fsu[(unsigned)st * (HID / 2) + lane];
            num0 += wt * bflo(u);
            num1 += wt * bfhi(u);
        }
    }
    denp += __shfl_xor(denp, 1, 64);
    denp += __shfl_xor(denp, 2, 64);
    denp += __shfl_xor(denp, 4, 64);
    float inv = 1.f / fmaxf(denp, 1e-9f);
    float v0 = num0 * inv, v1 = num1 * inv;
    v0 = (v0 > 0.f) ? v0 : (__expf(v0) - 1.f);
    v1 = (v1 > 0.f) ? v1 : (__expf(v1) - 1.f);
    *(float2*)&z[((size_t)d * NM + m) * HID + 2 * lane] = make_float2(v0, v1);
}

// -------- K4: w[r] = tanh(zel@W1 + b1) @ w2  (bf16 LDS A-tile; fp32 B from L2) ----
__global__ __launch_bounds__(256) void k_semw(const float* __restrict__ A,
                                              const float* __restrict__ B,
                                              const float* __restrict__ b1,
                                              const float* __restrict__ ws2,
                                              float* __restrict__ w) {
    __shared__ unsigned int As2[64 * LDP];
    int tid = threadIdx.x;
    int tc = tid & 15, tr = tid >> 4;
    int r0 = blockIdx.x * 64;
    int j0 = tc * 8;
    int rowA = tid & 63;
    int kc = tid >> 6;
    float acc[4][8];
    #pragma unroll
    for (int i = 0; i < 4; i++)
        #pragma unroll
        for (int c = 0; c < 8; c++) acc[i][c] = 0.f;

    int gr = r0 + rowA; if (gr > NROWS - 1) gr = NROWS - 1;
    const float* ap = A + (size_t)gr * HID + kc * 32;
    #pragma unroll
    for (int i = 0; i < 8; i++) {
        float4 v = ((const float4*)ap)[i];
        int kp = (kc * 32 + i * 4) >> 1;
        unsigned int p0 = (unsigned int)f2bf(v.x) | ((unsigned int)f2bf(v.y) << 16);
        unsigned int p1 = (unsigned int)f2bf(v.z) | ((unsigned int)f2bf(v.w) << 16);
        As2[kp * LDP + rowA] = p0;
        As2[(kp + 1) * LDP + rowA] = p1;
    }
    __syncthreads();
    const float* bp = B + j0;
    #pragma unroll 2
    for (int kp = 0; kp < 64; kp++) {
        uint4 aa = *(const uint4*)&As2[kp * LDP + tr * 4];
        int k0 = kp * 2;
        float aev[4] = {bflo(aa.x), bflo(aa.y), bflo(aa.z), bflo(aa.w)};
        float aov[4] = {bfhi(aa.x), bfhi(aa.y), bfhi(aa.z), bfhi(aa.w)};
        float4 b00 = *(const float4*)&bp[(size_t)k0 * HID];
        float4 b01 = *(const float4*)&bp[(size_t)k0 * HID + 4];
        float4 b10 = *(const float4*)&bp[(size_t)(k0 + 1) * HID];
        float4 b11 = *(const float4*)&bp[(size_t)(k0 + 1) * HID + 4];
        float bv0[8] = {b00.x, b00.y, b00.z, b00.w, b01.x, b01.y, b01.z, b01.w};
        float bv1[8] = {b10.x, b10.y, b10.z, b10.w, b11.x, b11.y, b11.z, b11.w};
        #pragma unroll
        for (int i = 0; i < 4; i++)
            #pragma unroll
            for (int c = 0; c < 8; c++)
                acc[i][c] += aev[i] * bv0[c] + aov[i] * bv1[c];
    }
    float bb[8], s2[8];
    #pragma unroll
    for (int c = 0; c < 8; c++) { bb[c] = b1[j0 + c]; s2[c] = ws2[j0 + c]; }
    #pragma unroll
    for (int i = 0; i < 4; i++) {
        float v = 0.f;
        #pragma unroll
        for (int c = 0; c < 8; c++) v += tanhf(acc[i][c] + bb[c]) * s2[c];
        #pragma unroll
        for (int o = 8; o > 0; o >>= 1) v += __shfl_down(v, o, 16);
        int row = r0 + tr * 4 + i;
        if (tc == 0 && row < NROWS) w[row] = v;
    }
}

// ---------------- K5: beta softmax + fused + out ----------------
__global__ __launch_bounds__(256) void k_comb(const float* __restrict__ zel,
                                              const float* __restrict__ w,
                                              const float* __restrict__ Wout,
                                              const float* __restrict__ bout,
                                              float* __restrict__ out) {
    __shared__ float fusedL[2][HID];
    int half = threadIdx.x >> 7;
    int j = threadIdx.x & 127;
    int n = blockIdx.x * 2 + half;
    float w0 = w[n * NM + 0];
    float w1 = w[n * NM + 1];
    float w2 = w[n * NM + 2];
    float mx = fmaxf(w0, fmaxf(w1, w2));
    float e0 = __expf(w0 - mx);
    float e1 = __expf(w1 - mx);
    float e2 = __expf(w2 - mx);
    float inv = 1.f / (e0 + e1 + e2);
    size_t base = (size_t)n * NM * HID;
    float f = (e0 * zel[base + j] + e1 * zel[base + HID + j] + e2 * zel[base + 2 * HID + j]) * inv;
    fusedL[half][j] = f;
    __syncthreads();
    int c = j >> 4, t16 = j & 15;
    float p = 0.f;
    #pragma unroll
    for (int i = 0; i < 8; i++) {
        int jj = t16 + i * 16;
        p += fusedL[half][jj] * Wout[jj * NOUT + c];
    }
    #pragma unroll
    for (int o = 8; o > 0; o >>= 1) p += __shfl_down(p, o, 16);
    if (t16 == 0) out[n * NOUT + c] = p + bout[c];
}

extern "C" void kernel_launch(void* const* d_in, const int* in_sizes, int n_in,
                              void* d_out, int out_size, void* d_ws, size_t ws_size,
                              hipStream_t stream) {
    (void)in_sizes; (void)n_in; (void)out_size; (void)ws_size;
    const float* feat  = (const float*)d_in[0];
    const float* Wfc   = (const float*)d_in[1];
    const float* bfc   = (const float*)d_in[2];
    const float* Wsrc  = (const float*)d_in[3];
    const float* Wdst  = (const float*)d_in[4];
    const float* al    = (const float*)d_in[5];
    const float* ar    = (const float*)d_in[6];
    const float* Wsem1 = (const float*)d_in[7];
    const float* bsem1 = (const float*)d_in[8];
    const float* wsem2 = (const float*)d_in[9];
    const float* Wout  = (const float*)d_in[10];
    const float* bout  = (const float*)d_in[11];
    const int* srcI    = (const int*)d_in[12];
    const int* dstI    = (const int*)d_in[13];
    float* out = (float*)d_out;

    // fp32 section.
    float* z    = (float*)d_ws;                       // NROWS*HID
    float* el   = z  + (size_t)NROWS * HID;           // NM*N_NODES*NH
    float* er   = el + (size_t)NM * N_NODES * NH;
    float* wsc  = er + (size_t)NM * N_NODES * NH;     // NROWS
    float* util = wsc + (size_t)NROWS;                // NM*HID*NH
    float* wtil = util + (size_t)NM * HID * NH;
    // packed bf16 hi/lo fragment planes
    unsigned short* wfcph = (unsigned short*)(wtil + (size_t)NM * HID * NH);
    unsigned short* wfcpl = wfcph + WFCP_N;
    unsigned short* wsph  = wfcpl + WFCP_N;
    unsigned short* wspl  = wsph + WSP_N;
    unsigned short* utph  = wspl + WSP_N;
    unsigned short* utpl  = utph + UTP_N;
    unsigned short* fs16  = utpl + UTP_N;             // NM*N_NODES*HID
    // int section
    int* deg    = (int*)(fs16 + (size_t)NM * N_NODES * HID);
    int* offs   = deg    + (size_t)NM * N_NODES;
    int* ssrc   = offs   + (size_t)NM * (N_NODES + 1);
    int* pfx    = ssrc   + (size_t)NM * NE;
    int* dstCur = pfx    + (size_t)NM * N_NODES;
    int* blksum = dstCur + (size_t)NM * N_NODES;
    int* blkbase= blksum + (size_t)NM * NBLK;
    int* binCur = blkbase+ (size_t)NM * NBLK;
    // pairs (NM*NE int2 = 19.2 MB) aliases the fs16 region (38.4 MB): the CSR
    // build fully consumes pairs before k_fcproj writes fs16 (same stream).
    int2* pairs = (int2*)fs16;

    // ---- CSR build ----
    hipMemsetAsync(deg, 0, (size_t)NM * N_NODES * sizeof(int), stream);
    {
        dim3 ge((NE + 255) / 256, NM);
        dim3 gs(NBLK, NM);
        k_hist<<<ge, 256, 0, stream>>>(dstI, deg);
        k_scan1<<<gs, 256, 0, stream>>>(deg, pfx, blksum);
        k_scan2<<<NM, 256, 0, stream>>>(blksum, blkbase);
        k_scan3<<<gs, 256, 0, stream>>>(pfx, blkbase, offs, dstCur, binCur);
        dim3 gb((NE + EPB - 1) / EPB, NM);
        k_binA2<<<gb, 256, 0, stream>>>(srcI, dstI, binCur, pairs);
        dim3 gc((NE + 255) / 256, NM);
        k_binB<<<gc, 256, 0, stream>>>(pairs, dstCur, ssrc);
    }

    k_attw<<<NM, 128, 0, stream>>>(Wsrc, Wdst, al, ar, util, wtil);
    k_pack<<<43, 256, 0, stream>>>(Wfc, Wsrc, util, wtil,
                                   wfcph, wfcpl, wsph, wspl, utph, utpl);
    k_fcproj<<<(N_NODES + 63) / 64, 256, 0, stream>>>(feat, bfc,
                                                      wfcph, wfcpl, wsph, wspl,
                                                      utph, utpl, fs16, el, er);
    {
        dim3 gg(N_NODES / 2, NM);
        k_gat<<<gg, 128, 0, stream>>>(ssrc, offs, el, er, fs16, z);
    }

    k_semw<<<(NROWS + 63) / 64, 256, 0, stream>>>(z, Wsem1, bsem1, wsem2, wsc);
    k_comb<<<N_NODES / 2, 256, 0, stream>>>(z, wsc, Wout, bout, out);
}

// Round 8
// 653.580 us; speedup vs baseline: 1.4344x; 1.0936x over previous
//
#include <hip/hip_runtime.h>
#include <hip/hip_bf16.h>
#include <stdint.h>

#define N_NODES 50000
#define F_IN 256
#define HID 128
#define NH 8
#define DH 16
#define NE 800000
#define NM 3
#define NOUT 8
#define NEG 0.2f
#define NROWS (N_NODES * NM)   // 150000 semantic rows
#define LDH 136                // padded bf16 stride for k_fcproj h-tile
#define NBLK 196               // ceil(50000/256) scan blocks
#define BSH 8                  // bucket shift: 256 dst per bucket
#define NBUCK 196              // ceil(50000/256)
#define EPB 8192               // edges per binning block

// pack sizes (u16 elements per plane)
#define WFCP_N 65536           // 8ct * 8ks * 64 * 8
#define WSP_N  98304           // 3m * 8ct * 4ks * 64 * 8
#define UTP_N  6144            // 3m * 4ks * 64 * 8
#define W1P_N  16384           // 8ct * 4ks * 64 * 8 (Wsem1)

typedef __attribute__((ext_vector_type(8))) short bfrag;
typedef __attribute__((ext_vector_type(4))) float f32x4;
union FU { uint4 u; bfrag b; };

#define MFMA(a, b, c) __builtin_amdgcn_mfma_f32_16x16x32_bf16(a, b, c, 0, 0, 0)

__device__ __forceinline__ float bf2f(unsigned short u) {
    union { unsigned int ui; float f; } cv;
    cv.ui = ((unsigned int)u) << 16;
    return cv.f;
}
__device__ __forceinline__ unsigned short f2bf(float x) {
    __hip_bfloat16 b = __float2bfloat16(x);
    return reinterpret_cast<const unsigned short&>(b);
}
__device__ __forceinline__ float bflo(unsigned int u) {
    union { unsigned int x; float f; } c; c.x = u << 16; return c.f;
}
__device__ __forceinline__ float bfhi(unsigned int u) {
    union { unsigned int x; float f; } c; c.x = u & 0xffff0000u; return c.f;
}

// ---------------- CSR build ----------------
__global__ __launch_bounds__(256) void k_hist(const int* __restrict__ dst,
                                              int* __restrict__ deg) {
    int e = blockIdx.x * 256 + threadIdx.x;
    int m = blockIdx.y;
    if (e >= NE) return;
    atomicAdd(&deg[m * N_NODES + dst[(size_t)m * NE + e]], 1);
}

__global__ __launch_bounds__(256) void k_scan1(const int* __restrict__ deg,
                                               int* __restrict__ pfx,
                                               int* __restrict__ blksum) {
    __shared__ int sc[256];
    int m = blockIdx.y, blk = blockIdx.x, t = threadIdx.x;
    int i = blk * 256 + t;
    int v = (i < N_NODES) ? deg[m * N_NODES + i] : 0;
    sc[t] = v;
    __syncthreads();
    #pragma unroll
    for (int o = 1; o < 256; o <<= 1) {
        int add = (t >= o) ? sc[t - o] : 0;
        __syncthreads();
        sc[t] += add;
        __syncthreads();
    }
    if (i < N_NODES) pfx[m * N_NODES + i] = sc[t] - v;
    if (t == 255) blksum[m * NBLK + blk] = sc[255];
}

__global__ __launch_bounds__(256) void k_scan2(const int* __restrict__ blksum,
                                               int* __restrict__ blkbase) {
    __shared__ int sc[256];
    int m = blockIdx.x, t = threadIdx.x;
    int v = (t < NBLK) ? blksum[m * NBLK + t] : 0;
    sc[t] = v;
    __syncthreads();
    #pragma unroll
    for (int o = 1; o < 256; o <<= 1) {
        int add = (t >= o) ? sc[t - o] : 0;
        __syncthreads();
        sc[t] += add;
        __syncthreads();
    }
    if (t < NBLK) blkbase[m * NBLK + t] = sc[t] - v;
}

__global__ __launch_bounds__(256) void k_scan3(const int* __restrict__ pfx,
                                               const int* __restrict__ blkbase,
                                               int* __restrict__ offs,
                                               int* __restrict__ dstCur,
                                               int* __restrict__ binCur) {
    int m = blockIdx.y, blk = blockIdx.x, t = threadIdx.x;
    int i = blk * 256 + t;
    if (i < N_NODES) {
        int o = blkbase[m * NBLK + blk] + pfx[m * N_NODES + i];
        offs[m * (N_NODES + 1) + i] = o;
        dstCur[m * N_NODES + i] = o;
        if ((i & 255) == 0) binCur[m * NBUCK + (i >> BSH)] = o;
    }
    if (i == 0) offs[m * (N_NODES + 1) + N_NODES] = NE;
}

// grid (ceil(NE/EPB), NM): all metapaths binned concurrently (separate pairs bufs)
__global__ __launch_bounds__(256) void k_binA2(const int* __restrict__ src0,
                                               const int* __restrict__ dst0,
                                               int* __restrict__ binCur0,
                                               int2* __restrict__ pairs0) {
    __shared__ int cnt[NBUCK];
    __shared__ int base[NBUCK];
    int m = blockIdx.y;
    const int* src = src0 + (size_t)m * NE;
    const int* dst = dst0 + (size_t)m * NE;
    int* binCur = binCur0 + (size_t)m * NBUCK;
    int2* pairs = pairs0 + (size_t)m * NE;
    int t = threadIdx.x;
    int e0 = blockIdx.x * EPB;
    int e1 = e0 + EPB; if (e1 > NE) e1 = NE;
    for (int i = t; i < NBUCK; i += 256) cnt[i] = 0;
    __syncthreads();
    for (int i = e0 + t; i < e1; i += 256)
        atomicAdd(&cnt[dst[i] >> BSH], 1);
    __syncthreads();
    for (int i = t; i < NBUCK; i += 256) {
        int c = cnt[i];
        base[i] = c ? atomicAdd(&binCur[i], c) : 0;
        cnt[i] = 0;
    }
    __syncthreads();
    for (int i = e0 + t; i < e1; i += 256) {
        int d = dst[i], s = src[i];
        int b = d >> BSH;
        int off = atomicAdd(&cnt[b], 1);
        pairs[base[b] + off] = make_int2(s, d);
    }
}

__global__ __launch_bounds__(256) void k_binB(const int2* __restrict__ pairs0,
                                              int* __restrict__ dstCur0,
                                              int* __restrict__ ssrc0) {
    int m = blockIdx.y;
    const int2* pairs = pairs0 + (size_t)m * NE;
    int* dstCur = dstCur0 + (size_t)m * N_NODES;
    int* ssrc = ssrc0 + (size_t)m * NE;
    int i = blockIdx.x * 256 + threadIdx.x;
    if (i >= NE) return;
    int2 p = pairs[i];
    int pos = atomicAdd(&dstCur[p.y], 1);
    ssrc[pos] = p.x;
}

// ---- K_attw: util[m][k][h] = sum_d Wsrc[m][k][h*16+d]*al[m][h*16+d]; same wtil/Wdst/ar ----
__global__ __launch_bounds__(128) void k_attw(const float* __restrict__ Wsrc,
                                              const float* __restrict__ Wdst,
                                              const float* __restrict__ al,
                                              const float* __restrict__ ar,
                                              float* __restrict__ util,
                                              float* __restrict__ wtil) {
    int m = blockIdx.x;
    int k = threadIdx.x;
    const float* ws = Wsrc + ((size_t)m * HID + k) * HID;
    const float* wd = Wdst + ((size_t)m * HID + k) * HID;
    const float* alm = al + m * HID;
    const float* arm = ar + m * HID;
    #pragma unroll
    for (int hh = 0; hh < NH; hh++) {
        float su = 0.f, sw = 0.f;
        #pragma unroll
        for (int d = 0; d < DH; d++) {
            su += ws[hh * DH + d] * alm[hh * DH + d];
            sw += wd[hh * DH + d] * arm[hh * DH + d];
        }
        util[((size_t)m * HID + k) * NH + hh] = su;
        wtil[((size_t)m * HID + k) * NH + hh] = sw;
    }
}

// ---- K_pack: pre-pack B matrices into MFMA fragment order as bf16 hi/lo planes.
// Fragment slot for K x N matrix (KS k-steps, CT col-tiles):
//   slot = (ct*KS + ks)*64 + lane; element j (0..7): k = ks*32 + (lane>>4)*8 + j,
//   n = ct*16 + (lane&15). hi = bf16(v), lo = bf16(v - fp32(hi)).
__global__ __launch_bounds__(256) void k_pack(const float* __restrict__ Wfc,
                                              const float* __restrict__ Wsrc,
                                              const float* __restrict__ util,
                                              const float* __restrict__ wtil,
                                              const float* __restrict__ Wsem1,
                                              unsigned short* __restrict__ wfcph,
                                              unsigned short* __restrict__ wfcpl,
                                              unsigned short* __restrict__ wsph,
                                              unsigned short* __restrict__ wspl,
                                              unsigned short* __restrict__ utph,
                                              unsigned short* __restrict__ utpl,
                                              unsigned short* __restrict__ w1ph,
                                              unsigned short* __restrict__ w1pl) {
    int g = blockIdx.x * 256 + threadIdx.x;
    if (blockIdx.x < 16) {                   // Wfc: 4096 slots (CT=8, KS=8)
        int s = g;
        int lane = s & 63, t = s >> 6;
        int ks = t & 7, ct = t >> 3;
        int n = ct * 16 + (lane & 15);
        int kb = ks * 32 + ((lane >> 4) << 3);
        #pragma unroll
        for (int j = 0; j < 8; j++) {
            float v = Wfc[(size_t)(kb + j) * HID + n];
            unsigned short h = f2bf(v);
            wfcph[(size_t)s * 8 + j] = h;
            wfcpl[(size_t)s * 8 + j] = f2bf(v - bf2f(h));
        }
    } else if (blockIdx.x < 40) {            // Wsrc: 6144 slots (3m, CT=8, KS=4)
        int s = g - 16 * 256;
        int lane = s & 63, t = s >> 6;
        int ks = t & 3, ct = (t >> 2) & 7, m = t >> 5;
        int n = ct * 16 + (lane & 15);
        int kb = ks * 32 + ((lane >> 4) << 3);
        #pragma unroll
        for (int j = 0; j < 8; j++) {
            float v = Wsrc[((size_t)m * HID + kb + j) * HID + n];
            unsigned short h = f2bf(v);
            wsph[(size_t)s * 8 + j] = h;
            wspl[(size_t)s * 8 + j] = f2bf(v - bf2f(h));
        }
    } else if (blockIdx.x < 43) {            // util|wtil: 768 slots (3m, CT=1, KS=4)
        int s = g - 40 * 256;
        if (s >= UTP_N / 8) return;
        int lane = s & 63, t = s >> 6;
        int ks = t & 3, m = t >> 2;
        int n = lane & 15;
        int kb = ks * 32 + ((lane >> 4) << 3);
        #pragma unroll
        for (int j = 0; j < 8; j++) {
            int k = kb + j;
            float v = (n < 8) ? util[((size_t)m * HID + k) * NH + n]
                              : wtil[((size_t)m * HID + k) * NH + (n - 8)];
            unsigned short h = f2bf(v);
            utph[(size_t)s * 8 + j] = h;
            utpl[(size_t)s * 8 + j] = f2bf(v - bf2f(h));
        }
    } else {                                 // Wsem1: 2048 slots (CT=8, KS=4)
        int s = g - 43 * 256;
        int lane = s & 63, t = s >> 6;
        int ks = t & 3, ct = t >> 2;
        int n = ct * 16 + (lane & 15);
        int kb = ks * 32 + ((lane >> 4) << 3);
        #pragma unroll
        for (int j = 0; j < 8; j++) {
            float v = Wsem1[(size_t)(kb + j) * HID + n];
            unsigned short h = f2bf(v);
            w1ph[(size_t)s * 8 + j] = h;
            w1pl[(size_t)s * 8 + j] = f2bf(v - bf2f(h));
        }
    }
}

// ---- K1+K2 fused, MFMA version. 64 rows/block, 4 waves, wave w owns rows
// r0+16w..+15 end-to-end (NO barriers; waves independent).
// Phase 1: h = feat @ Wfc via bf16x2 split (AhBh + AhBl + AlBh; AlBl ~2^-18
// dropped) -> fp32-faithful h. Phase 2: bf16(h + bias) -> LDS (the exact values
// downstream already consumed). Phase 3 per metapath: fs16 = bf16(h @ Wsrc)
// and el/er = h @ (util|wtil) via A-exact x (Bhi + Blo) 2-pass MFMA.
// MFMA layouts (m89/m91, HW-verified here in round 7): A lane&15=row,
// k=(lane>>4)*8+j; C col=lane&15, row=(lane>>4)*4+reg.
__global__ __launch_bounds__(256) void k_fcproj(const float* __restrict__ A,
                                                const float* __restrict__ bias,
                                                const unsigned short* __restrict__ wfcph,
                                                const unsigned short* __restrict__ wfcpl,
                                                const unsigned short* __restrict__ wsph,
                                                const unsigned short* __restrict__ wspl,
                                                const unsigned short* __restrict__ utph,
                                                const unsigned short* __restrict__ utpl,
                                                unsigned short* __restrict__ fs0,
                                                float* __restrict__ el0,
                                                float* __restrict__ er0) {
    __shared__ unsigned short hb[64 * LDH];   // 17.4 KB bf16 h-tile
    int tid = threadIdx.x;
    int w = tid >> 6, l = tid & 63;
    int lr = l & 15;       // A-row / C-col lane index
    int lq = l >> 4;       // k-block / C-row-quad index
    int r0 = blockIdx.x * 64;
    int rowA = r0 + 16 * w + lr;
    int gr = (rowA < N_NODES) ? rowA : (N_NODES - 1);

    // ---- phase 1: h-tile = feat @ Wfc (split-precision MFMA) ----
    f32x4 acc[8];
    #pragma unroll
    for (int ct = 0; ct < 8; ct++) acc[ct] = (f32x4){0.f, 0.f, 0.f, 0.f};
    const uint4* bh4 = (const uint4*)wfcph;
    const uint4* bl4 = (const uint4*)wfcpl;
    for (int ks = 0; ks < 8; ks++) {
        const float* ap = A + (size_t)gr * F_IN + ks * 32 + lq * 8;
        float4 v0 = ((const float4*)ap)[0];
        float4 v1 = ((const float4*)ap)[1];
        float av[8] = {v0.x, v0.y, v0.z, v0.w, v1.x, v1.y, v1.z, v1.w};
        bfrag ah, al;
        #pragma unroll
        for (int j = 0; j < 8; j++) {
            unsigned short h = f2bf(av[j]);
            ah[j] = (short)h;
            al[j] = (short)f2bf(av[j] - bf2f(h));
        }
        #pragma unroll
        for (int ct = 0; ct < 8; ct++) {
            FU bh, bl;
            bh.u = bh4[(ct * 8 + ks) * 64 + l];
            bl.u = bl4[(ct * 8 + ks) * 64 + l];
            acc[ct] = MFMA(ah, bh.b, acc[ct]);
            acc[ct] = MFMA(ah, bl.b, acc[ct]);
            acc[ct] = MFMA(al, bh.b, acc[ct]);
        }
    }
    // ---- phase 2: bf16(h + bias) -> LDS (wave-private rows; no barrier) ----
    #pragma unroll
    for (int ct = 0; ct < 8; ct++) {
        int col = ct * 16 + lr;
        float bb = bias[col];
        #pragma unroll
        for (int rg = 0; rg < 4; rg++) {
            int rloc = 16 * w + lq * 4 + rg;
            hb[rloc * LDH + col] = f2bf(acc[ct][rg] + bb);
        }
    }
    // ---- phase 3: per-metapath fs16 / el / er ----
    const uint4* sh4 = (const uint4*)wsph;
    const uint4* sl4 = (const uint4*)wspl;
    const uint4* uh4 = (const uint4*)utph;
    const uint4* ul4 = (const uint4*)utpl;
    for (int m = 0; m < NM; m++) {
        f32x4 acc2[8];
        f32x4 eacc = (f32x4){0.f, 0.f, 0.f, 0.f};
        #pragma unroll
        for (int ct = 0; ct < 8; ct++) acc2[ct] = (f32x4){0.f, 0.f, 0.f, 0.f};
        #pragma unroll
        for (int ks = 0; ks < 4; ks++) {
            FU a;
            a.u = *(const uint4*)&hb[(16 * w + lr) * LDH + ks * 32 + lq * 8];
            #pragma unroll
            for (int ct = 0; ct < 8; ct++) {
                FU bh, bl;
                bh.u = sh4[(m * 32 + ct * 4 + ks) * 64 + l];
                bl.u = sl4[(m * 32 + ct * 4 + ks) * 64 + l];
                acc2[ct] = MFMA(a.b, bh.b, acc2[ct]);
                acc2[ct] = MFMA(a.b, bl.b, acc2[ct]);
            }
            FU uh, ul;
            uh.u = uh4[(m * 4 + ks) * 64 + l];
            ul.u = ul4[(m * 4 + ks) * 64 + l];
            eacc = MFMA(a.b, uh.b, eacc);
            eacc = MFMA(a.b, ul.b, eacc);
        }
        unsigned short* fsm = fs0 + (size_t)m * N_NODES * HID;
        #pragma unroll
        for (int ct = 0; ct < 8; ct++) {
            #pragma unroll
            for (int rg = 0; rg < 4; rg++) {
                int row = r0 + 16 * w + lq * 4 + rg;
                if (row < N_NODES)
                    fsm[(size_t)row * HID + ct * 16 + lr] = f2bf(acc2[ct][rg]);
            }
        }
        float* elm = el0 + (size_t)m * N_NODES * NH;
        float* erm = er0 + (size_t)m * N_NODES * NH;
        #pragma unroll
        for (int rg = 0; rg < 4; rg++) {
            int row = r0 + 16 * w + lq * 4 + rg;
            if (row < N_NODES) {
                if (lr < 8) elm[(size_t)row * NH + lr] = eacc[rg];
                else        erm[(size_t)row * NH + (lr - 8)] = eacc[rg];
            }
        }
    }
}

// ---- K3: per-dst GAT aggregation. One WAVE per dst (2 dst per 128-thr block).
// (Round-1 body — best measured.)
__global__ __launch_bounds__(128) void k_gat(const int* __restrict__ ssrc0,
                                             const int* __restrict__ offs0,
                                             const float* __restrict__ el0,
                                             const float* __restrict__ er0,
                                             const unsigned short* __restrict__ fs0,
                                             float* __restrict__ z) {
    int m = blockIdx.y;
    const int* ssrc = ssrc0 + (size_t)m * NE;
    const int* offs = offs0 + (size_t)m * (N_NODES + 1);
    const float* el = el0 + (size_t)m * N_NODES * NH;
    const float* er = er0 + (size_t)m * N_NODES * NH;
    const unsigned int* fsu = (const unsigned int*)(fs0 + (size_t)m * N_NODES * HID);
    int d = blockIdx.x * 2 + (threadIdx.x >> 6);
    int lane = threadIdx.x & 63;
    int hh = lane >> 3;          // head for features 2*lane, 2*lane+1
    int sub = lane & 7;          // edge slot within an 8-edge chunk
    int gbase = lane & 56;       // head-group base lane
    int s0 = offs[d], s1 = offs[d + 1];
    float erd = er[(unsigned)d * NH + hh];
    float num0 = 0.f, num1 = 0.f, denp = 0.f;
    int base = s0;
    for (; base + 8 <= s1; base += 8) {
        int s = ssrc[base + sub];
        float x = el[(unsigned)s * NH + hh] + erd;
        x = (x >= 0.f) ? x : NEG * x;
        float w = __expf(x);
        denp += w;
        #pragma unroll
        for (int t = 0; t < 8; t++) {
            int st = __shfl(s, gbase + t, 64);
            float wt = __shfl(w, gbase + t, 64);
            unsigned int u = fsu[(unsigned)st * (HID / 2) + lane];
            num0 += wt * bflo(u);
            num1 += wt * bfhi(u);
        }
    }
    int n = s1 - base;
    if (n > 0) {
        int s = ssrc[base + ((sub < n) ? sub : n - 1)];
        float x = el[(unsigned)s * NH + hh] + erd;
        x = (x >= 0.f) ? x : NEG * x;
        float w = (sub < n) ? __expf(x) : 0.f;
        denp += w;
        #pragma unroll 2
        for (int t = 0; t < n; t++) {
            int st = __shfl(s, gbase + t, 64);
            float wt = __shfl(w, gbase + t, 64);
            unsigned int u = fsu[(unsigned)st * (HID / 2) + lane];
            num0 += wt * bflo(u);
            num1 += wt * bfhi(u);
        }
    }
    denp += __shfl_xor(denp, 1, 64);
    denp += __shfl_xor(denp, 2, 64);
    denp += __shfl_xor(denp, 4, 64);
    float inv = 1.f / fmaxf(denp, 1e-9f);
    float v0 = num0 * inv, v1 = num1 * inv;
    v0 = (v0 > 0.f) ? v0 : (__expf(v0) - 1.f);
    v1 = (v1 > 0.f) ? v1 : (__expf(v1) - 1.f);
    *(float2*)&z[((size_t)d * NM + m) * HID + 2 * lane] = make_float2(v0, v1);
}

// -------- K4 (MFMA): w[r] = tanh(bf16(z[r]) @ (W1h + W1l) + b1) @ w2.
// A = bf16(z) — identical values to the old LDS-tile path; B split hi/lo 2-pass
// matches fp32 B to ~2^-17, so numerics are unchanged vs the VALU version.
// Old version re-streamed 4 KB of W1 per thread-tile (~2.3 GB L1 traffic,
// ~31 us fp32-FMA floor); MFMA cuts both. No LDS, no barriers; wave-private
// 16-row tiles; epilogue reduces cols across the 16-lane lr group.
__global__ __launch_bounds__(256) void k_semw(const float* __restrict__ A,
                                              const unsigned short* __restrict__ w1ph,
                                              const unsigned short* __restrict__ w1pl,
                                              const float* __restrict__ b1,
                                              const float* __restrict__ ws2,
                                              float* __restrict__ w) {
    int tid = threadIdx.x;
    int wv = tid >> 6, l = tid & 63;
    int lr = l & 15;
    int lq = l >> 4;
    int tbase = blockIdx.x * 64 + wv * 16;
    int rowA = tbase + lr;
    int gr = (rowA < NROWS) ? rowA : (NROWS - 1);
    const uint4* bh4 = (const uint4*)w1ph;
    const uint4* bl4 = (const uint4*)w1pl;
    f32x4 acc[8];
    #pragma unroll
    for (int ct = 0; ct < 8; ct++) acc[ct] = (f32x4){0.f, 0.f, 0.f, 0.f};
    #pragma unroll
    for (int ks = 0; ks < 4; ks++) {
        const float* ap = A + (size_t)gr * HID + ks * 32 + lq * 8;
        float4 v0 = ((const float4*)ap)[0];
        float4 v1 = ((const float4*)ap)[1];
        float av[8] = {v0.x, v0.y, v0.z, v0.w, v1.x, v1.y, v1.z, v1.w};
        bfrag a;
        #pragma unroll
        for (int j = 0; j < 8; j++) a[j] = (short)f2bf(av[j]);
        #pragma unroll
        for (int ct = 0; ct < 8; ct++) {
            FU bh, bl;
            bh.u = bh4[(ct * 4 + ks) * 64 + l];
            bl.u = bl4[(ct * 4 + ks) * 64 + l];
            acc[ct] = MFMA(a, bh.b, acc[ct]);
            acc[ct] = MFMA(a, bl.b, acc[ct]);
        }
    }
    // epilogue: per lane cols {ct*16+lr}, rows {lq*4+rg}; tanh-dot then
    // reduce across the 16 lanes (lr) sharing this lq.
    float bb[8], s2[8];
    #pragma unroll
    for (int ct = 0; ct < 8; ct++) {
        bb[ct] = b1[ct * 16 + lr];
        s2[ct] = ws2[ct * 16 + lr];
    }
    #pragma unroll
    for (int rg = 0; rg < 4; rg++) {
        float v = 0.f;
        #pragma unroll
        for (int ct = 0; ct < 8; ct++)
            v += tanhf(acc[ct][rg] + bb[ct]) * s2[ct];
        v += __shfl_xor(v, 1, 64);
        v += __shfl_xor(v, 2, 64);
        v += __shfl_xor(v, 4, 64);
        v += __shfl_xor(v, 8, 64);
        int row = tbase + lq * 4 + rg;
        if (lr == 0 && row < NROWS) w[row] = v;
    }
}

// ---------------- K5: beta softmax + fused + out ----------------
__global__ __launch_bounds__(256) void k_comb(const float* __restrict__ zel,
                                              const float* __restrict__ w,
                                              const float* __restrict__ Wout,
                                              const float* __restrict__ bout,
                                              float* __restrict__ out) {
    __shared__ float fusedL[2][HID];
    int half = threadIdx.x >> 7;
    int j = threadIdx.x & 127;
    int n = blockIdx.x * 2 + half;
    float w0 = w[n * NM + 0];
    float w1 = w[n * NM + 1];
    float w2 = w[n * NM + 2];
    float mx = fmaxf(w0, fmaxf(w1, w2));
    float e0 = __expf(w0 - mx);
    float e1 = __expf(w1 - mx);
    float e2 = __expf(w2 - mx);
    float inv = 1.f / (e0 + e1 + e2);
    size_t base = (size_t)n * NM * HID;
    float f = (e0 * zel[base + j] + e1 * zel[base + HID + j] + e2 * zel[base + 2 * HID + j]) * inv;
    fusedL[half][j] = f;
    __syncthreads();
    int c = j >> 4, t16 = j & 15;
    float p = 0.f;
    #pragma unroll
    for (int i = 0; i < 8; i++) {
        int jj = t16 + i * 16;
        p += fusedL[half][jj] * Wout[jj * NOUT + c];
    }
    #pragma unroll
    for (int o = 8; o > 0; o >>= 1) p += __shfl_down(p, o, 16);
    if (t16 == 0) out[n * NOUT + c] = p + bout[c];
}

extern "C" void kernel_launch(void* const* d_in, const int* in_sizes, int n_in,
                              void* d_out, int out_size, void* d_ws, size_t ws_size,
                              hipStream_t stream) {
    (void)in_sizes; (void)n_in; (void)out_size; (void)ws_size;
    const float* feat  = (const float*)d_in[0];
    const float* Wfc   = (const float*)d_in[1];
    const float* bfc   = (const float*)d_in[2];
    const float* Wsrc  = (const float*)d_in[3];
    const float* Wdst  = (const float*)d_in[4];
    const float* al    = (const float*)d_in[5];
    const float* ar    = (const float*)d_in[6];
    const float* Wsem1 = (const float*)d_in[7];
    const float* bsem1 = (const float*)d_in[8];
    const float* wsem2 = (const float*)d_in[9];
    const float* Wout  = (const float*)d_in[10];
    const float* bout  = (const float*)d_in[11];
    const int* srcI    = (const int*)d_in[12];
    const int* dstI    = (const int*)d_in[13];
    float* out = (float*)d_out;

    // fp32 section.
    float* z    = (float*)d_ws;                       // NROWS*HID
    float* el   = z  + (size_t)NROWS * HID;           // NM*N_NODES*NH
    float* er   = el + (size_t)NM * N_NODES * NH;
    float* wsc  = er + (size_t)NM * N_NODES * NH;     // NROWS
    float* util = wsc + (size_t)NROWS;                // NM*HID*NH
    float* wtil = util + (size_t)NM * HID * NH;
    // packed bf16 hi/lo fragment planes
    unsigned short* wfcph = (unsigned short*)(wtil + (size_t)NM * HID * NH);
    unsigned short* wfcpl = wfcph + WFCP_N;
    unsigned short* wsph  = wfcpl + WFCP_N;
    unsigned short* wspl  = wsph + WSP_N;
    unsigned short* utph  = wspl + WSP_N;
    unsigned short* utpl  = utph + UTP_N;
    unsigned short* w1ph  = utpl + UTP_N;
    unsigned short* w1pl  = w1ph + W1P_N;
    unsigned short* fs16  = w1pl + W1P_N;             // NM*N_NODES*HID
    // int section
    int* deg    = (int*)(fs16 + (size_t)NM * N_NODES * HID);
    int* offs   = deg    + (size_t)NM * N_NODES;
    int* ssrc   = offs   + (size_t)NM * (N_NODES + 1);
    int* pfx    = ssrc   + (size_t)NM * NE;
    int* dstCur = pfx    + (size_t)NM * N_NODES;
    int* blksum = dstCur + (size_t)NM * N_NODES;
    int* blkbase= blksum + (size_t)NM * NBLK;
    int* binCur = blkbase+ (size_t)NM * NBLK;
    // pairs (NM*NE int2 = 19.2 MB) aliases the fs16 region (38.4 MB): the CSR
    // build fully consumes pairs before k_fcproj writes fs16 (same stream).
    int2* pairs = (int2*)fs16;

    // ---- CSR build ----
    hipMemsetAsync(deg, 0, (size_t)NM * N_NODES * sizeof(int), stream);
    {
        dim3 ge((NE + 255) / 256, NM);
        dim3 gs(NBLK, NM);
        k_hist<<<ge, 256, 0, stream>>>(dstI, deg);
        k_scan1<<<gs, 256, 0, stream>>>(deg, pfx, blksum);
        k_scan2<<<NM, 256, 0, stream>>>(blksum, blkbase);
        k_scan3<<<gs, 256, 0, stream>>>(pfx, blkbase, offs, dstCur, binCur);
        dim3 gb((NE + EPB - 1) / EPB, NM);
        k_binA2<<<gb, 256, 0, stream>>>(srcI, dstI, binCur, pairs);
        dim3 gc((NE + 255) / 256, NM);
        k_binB<<<gc, 256, 0, stream>>>(pairs, dstCur, ssrc);
    }

    k_attw<<<NM, 128, 0, stream>>>(Wsrc, Wdst, al, ar, util, wtil);
    k_pack<<<51, 256, 0, stream>>>(Wfc, Wsrc, util, wtil, Wsem1,
                                   wfcph, wfcpl, wsph, wspl, utph, utpl,
                                   w1ph, w1pl);
    k_fcproj<<<(N_NODES + 63) / 64, 256, 0, stream>>>(feat, bfc,
                                                      wfcph, wfcpl, wsph, wspl,
                                                      utph, utpl, fs16, el, er);
    {
        dim3 gg(N_NODES / 2, NM);
        k_gat<<<gg, 128, 0, stream>>>(ssrc, offs, el, er, fs16, z);
    }

    k_semw<<<(NROWS + 63) / 64, 256, 0, stream>>>(z, w1ph, w1pl, bsem1, wsem2, wsc);
    k_comb<<<N_NODES / 2, 256, 0, stream>>>(z, wsc, Wout, bout, out);
}